// Round 5
// baseline (618.225 us; speedup 1.0000x reference)
//
#include <hip/hip_runtime.h>
#include <cstdint>

typedef unsigned short u16;
typedef unsigned int u32;
typedef __attribute__((ext_vector_type(4))) float f32x4;
typedef __attribute__((ext_vector_type(8))) __bf16 bf16x8;
typedef __attribute__((ext_vector_type(8))) unsigned short u16x8;
typedef __attribute__((ext_vector_type(4))) unsigned int u32x4;

#define S_LEN 2048
#define BATCH 2
#define NQH 32
#define NKVH 8
#define HD 96
#define EMB 3072
#define QKVN 4608
#define KOFF 3072
#define VOFF 3840
#define KSP 104  // Ks row pad (u16): 208B rows -> 52dw = 20 mod 32, full bank coset

__device__ __forceinline__ u16 f2b(float f) {
    u32 u = __float_as_uint(f);
    u32 r = (u + 0x7fffu + ((u >> 16) & 1u)) >> 16;
    return (u16)r;
}
__device__ __forceinline__ float b2f(u16 h) { return __uint_as_float(((u32)h) << 16); }
__device__ __forceinline__ u32 cvtpk(float lo, float hi) {
    u32 r;
    asm("v_cvt_pk_bf16_f32 %0, %1, %2" : "=v"(r) : "v"(lo), "v"(hi));
    return r;
}

// ---------------- fp32 -> bf16 bulk convert ----------------
__global__ __launch_bounds__(256) void conv_f2b(const float* __restrict__ in,
                                                u16* __restrict__ outp, int n8) {
    const int i = blockIdx.x * 256 + threadIdx.x;
    if (i >= n8) return;
    const f32x4* q = (const f32x4*)(in + (size_t)i * 8);
    const f32x4 a = q[0], b = q[1];
    u16x8 t;
#pragma unroll
    for (int j = 0; j < 4; ++j) {
        t[j] = f2b(a[j]);
        t[j + 4] = f2b(b[j]);
    }
    *(u16x8*)(outp + (size_t)i * 8) = t;
}

// ---------------- async global->LDS helper ----------------
typedef __attribute__((address_space(1))) const uint32_t gas_u32;
typedef __attribute__((address_space(3))) uint32_t las_u32;
__device__ __forceinline__ void gld_lds16(const u16* g, u16* l) {
    __builtin_amdgcn_global_load_lds((gas_u32*)g, (las_u32*)l, 16, 0, 0);
}

#define WAITV4 asm volatile("s_waitcnt vmcnt(4)" ::: "memory")
#define WAITV0 asm volatile("s_waitcnt vmcnt(0)" ::: "memory")
#define BARRIER __builtin_amdgcn_s_barrier()
#define SCHEDB __builtin_amdgcn_sched_barrier(0)

// ---------------- Pipelined GEMM: C[M,N] = A[M,K] * B[N,K]^T ----------------
// 128x128 tile, BK=64, double-buffered LDS, counted vmcnt(4), XOR-swizzled LDS.
// + T1 bijective XCD swizzle (active when nwg % 8 == 0).
template <bool OUTF32>
__global__ __launch_bounds__(256, 2) void gemm_bt_p(const u16* __restrict__ Ap,
                                                    const u16* __restrict__ Bp,
                                                    void* __restrict__ Cp,
                                                    int M, int N, int K, int ldc) {
    __shared__ __align__(16) u16 S[2 * 16384];  // 64 KB: [buf][A/B 8192][khalf 4096]
    const int tid = threadIdx.x;
    const int wave = tid >> 6, lane = tid & 63;
    const int lrow = lane & 15, lhi = lane >> 4;

    int bxi = blockIdx.x, byi = blockIdx.y;
    {
        const int gx = gridDim.x;
        const int nwg = gx * gridDim.y;
        if ((nwg & 7) == 0) {
            int fid = byi * gx + bxi;
            fid = (fid & 7) * (nwg >> 3) + (fid >> 3);
            bxi = fid % gx;
            byi = fid / gx;
        }
    }
    const int bm = byi * 128, bn = bxi * 128;
    const int wm = (wave >> 1) * 64, wn = (wave & 1) * 64;
    const int xsl = ((lhi ^ (lrow & 3) ^ ((lrow >> 2) & 3)) << 3);
    const int srow = tid >> 2;
    const int scol = (((tid & 3) ^ ((tid >> 2) & 3) ^ ((tid >> 4) & 3))) * 8;
    const u16* gA0 = Ap + (size_t)(bm + srow) * K + scol;
    const u16* gA1 = Ap + (size_t)(bm + 64 + srow) * K + scol;
    const u16* gB0 = Bp + (size_t)(bn + srow) * K + scol;
    const u16* gB1 = Bp + (size_t)(bn + 64 + srow) * K + scol;
    u16* const dbase = S + (tid & 192) * 8;

    f32x4 acc[4][4] = {};
    const int nt = K >> 6;

    gld_lds16(gA0, dbase);
    gld_lds16(gA1, dbase + 2048);
    gld_lds16(gB0, dbase + 8192);
    gld_lds16(gB1, dbase + 8192 + 2048);
    gld_lds16(gA0 + 32, dbase + 4096);
    gld_lds16(gA1 + 32, dbase + 4096 + 2048);
    gld_lds16(gB0 + 32, dbase + 8192 + 4096);
    gld_lds16(gB1 + 32, dbase + 8192 + 4096 + 2048);

    for (int t = 0; t + 1 < nt; ++t) {
        const int cur = t & 1;
        const u16* Ab = S + cur * 16384;
        const u16* Bb = Ab + 8192;
        u16* dn = dbase + (cur ^ 1) * 16384;
        const int ko = (t + 1) << 6;

        WAITV4;
        BARRIER;
        SCHEDB;
        gld_lds16(gA0 + ko, dn);
        gld_lds16(gA1 + ko, dn + 2048);
        bf16x8 af[4], bf0[2], bf1[2];
#pragma unroll
        for (int mi = 0; mi < 4; ++mi)
            af[mi] = *(const bf16x8*)(Ab + (wm + mi * 16 + lrow) * 32 + xsl);
#pragma unroll
        for (int ni = 0; ni < 2; ++ni)
            bf0[ni] = *(const bf16x8*)(Bb + (wn + ni * 16 + lrow) * 32 + xsl);
        __builtin_amdgcn_s_setprio(1);
#pragma unroll
        for (int mi = 0; mi < 4; ++mi)
#pragma unroll
            for (int ni = 0; ni < 2; ++ni)
                acc[mi][ni] = __builtin_amdgcn_mfma_f32_16x16x32_bf16(af[mi], bf0[ni],
                                                                      acc[mi][ni], 0, 0, 0);
        __builtin_amdgcn_s_setprio(0);
        gld_lds16(gB0 + ko, dn + 8192);
        gld_lds16(gB1 + ko, dn + 8192 + 2048);
#pragma unroll
        for (int ni = 0; ni < 2; ++ni)
            bf1[ni] = *(const bf16x8*)(Bb + (wn + (ni + 2) * 16 + lrow) * 32 + xsl);
        __builtin_amdgcn_s_setprio(1);
#pragma unroll
        for (int mi = 0; mi < 4; ++mi)
#pragma unroll
            for (int ni = 0; ni < 2; ++ni)
                acc[mi][ni + 2] = __builtin_amdgcn_mfma_f32_16x16x32_bf16(af[mi], bf1[ni],
                                                                          acc[mi][ni + 2], 0, 0, 0);
        __builtin_amdgcn_s_setprio(0);

        WAITV4;
        BARRIER;
        SCHEDB;
        gld_lds16(gA0 + ko + 32, dn + 4096);
        gld_lds16(gA1 + ko + 32, dn + 4096 + 2048);
#pragma unroll
        for (int mi = 0; mi < 4; ++mi)
            af[mi] = *(const bf16x8*)(Ab + 4096 + (wm + mi * 16 + lrow) * 32 + xsl);
#pragma unroll
        for (int ni = 0; ni < 2; ++ni)
            bf0[ni] = *(const bf16x8*)(Bb + 4096 + (wn + ni * 16 + lrow) * 32 + xsl);
        __builtin_amdgcn_s_setprio(1);
#pragma unroll
        for (int mi = 0; mi < 4; ++mi)
#pragma unroll
            for (int ni = 0; ni < 2; ++ni)
                acc[mi][ni] = __builtin_amdgcn_mfma_f32_16x16x32_bf16(af[mi], bf0[ni],
                                                                      acc[mi][ni], 0, 0, 0);
        __builtin_amdgcn_s_setprio(0);
        gld_lds16(gB0 + ko + 32, dn + 8192 + 4096);
        gld_lds16(gB1 + ko + 32, dn + 8192 + 4096 + 2048);
#pragma unroll
        for (int ni = 0; ni < 2; ++ni)
            bf1[ni] = *(const bf16x8*)(Bb + 4096 + (wn + (ni + 2) * 16 + lrow) * 32 + xsl);
        __builtin_amdgcn_s_setprio(1);
#pragma unroll
        for (int mi = 0; mi < 4; ++mi)
#pragma unroll
            for (int ni = 0; ni < 2; ++ni)
                acc[mi][ni + 2] = __builtin_amdgcn_mfma_f32_16x16x32_bf16(af[mi], bf1[ni],
                                                                          acc[mi][ni + 2], 0, 0, 0);
        __builtin_amdgcn_s_setprio(0);
    }

    {
        const int cur = (nt - 1) & 1;
        const u16* Ab = S + cur * 16384;
        const u16* Bb = Ab + 8192;
        WAITV4;
        BARRIER;
        SCHEDB;
        bf16x8 af[4], bfr[4];
#pragma unroll
        for (int mi = 0; mi < 4; ++mi)
            af[mi] = *(const bf16x8*)(Ab + (wm + mi * 16 + lrow) * 32 + xsl);
#pragma unroll
        for (int ni = 0; ni < 4; ++ni)
            bfr[ni] = *(const bf16x8*)(Bb + (wn + ni * 16 + lrow) * 32 + xsl);
#pragma unroll
        for (int mi = 0; mi < 4; ++mi)
#pragma unroll
            for (int ni = 0; ni < 4; ++ni)
                acc[mi][ni] = __builtin_amdgcn_mfma_f32_16x16x32_bf16(af[mi], bfr[ni],
                                                                      acc[mi][ni], 0, 0, 0);
        WAITV0;
        BARRIER;
        SCHEDB;
#pragma unroll
        for (int mi = 0; mi < 4; ++mi)
            af[mi] = *(const bf16x8*)(Ab + 4096 + (wm + mi * 16 + lrow) * 32 + xsl);
#pragma unroll
        for (int ni = 0; ni < 4; ++ni)
            bfr[ni] = *(const bf16x8*)(Bb + 4096 + (wn + ni * 16 + lrow) * 32 + xsl);
#pragma unroll
        for (int mi = 0; mi < 4; ++mi)
#pragma unroll
            for (int ni = 0; ni < 4; ++ni)
                acc[mi][ni] = __builtin_amdgcn_mfma_f32_16x16x32_bf16(af[mi], bfr[ni],
                                                                      acc[mi][ni], 0, 0, 0);
    }

    const int orow = bm + wm + lhi * 4;
    const int ocol = bn + wn + lrow;
#pragma unroll
    for (int mi = 0; mi < 4; ++mi)
#pragma unroll
        for (int ni = 0; ni < 4; ++ni)
#pragma unroll
            for (int r = 0; r < 4; ++r) {
                const size_t idx = (size_t)(orow + mi * 16 + r) * ldc + ocol + ni * 16;
                if constexpr (OUTF32)
                    ((float*)Cp)[idx] = acc[mi][ni][r];
                else
                    ((u16*)Cp)[idx] = f2b(acc[mi][ni][r]);
            }
}

// ---------------- RoPE in-place on q,k of bf16 qkv ----------------
__global__ __launch_bounds__(256) void gqa_rope(u16* __restrict__ qkv,
                                                const int* __restrict__ positions) {
    int i = blockIdx.x * 256 + threadIdx.x;
    const int pair = i % 48;
    int t = i / 48;
    const int head = t % (NQH + NKVH);
    const int bs = t / (NQH + NKVH);
    const int pos = positions[bs & (S_LEN - 1)];
    const size_t base = (size_t)bs * QKVN + (head < NQH ? head * HD : KOFF + (head - NQH) * HD);
    const float invf = __expf(-(float)(2 * pair) * (1.0f / 96.0f) * 9.210340371976184f);
    const float ang = (float)pos * invf;
    float sn, cs;
    __sincosf(ang, &sn, &cs);
    const float t1 = b2f(qkv[base + pair]);
    const float t2 = b2f(qkv[base + 48 + pair]);
    qkv[base + pair] = f2b(t1 * cs - t2 * sn);
    qkv[base + 48 + pair] = f2b(t2 * cs + t1 * sn);
}

// ---------------- Flash GQA v5: T14 async-stage + V de-gather + Ks pad ----------------
__global__ __launch_bounds__(256) void gqa_attn5(const u16* __restrict__ qkv,
                                                 u16* __restrict__ out) {
    __shared__ __align__(16) u16 Ks[64 * KSP];   // 13.0 KB (padded rows)
    __shared__ __align__(16) u16 Vtmp[64 * 96];  // 12.0 KB row-major V
    __shared__ __align__(16) u16 Vt[96 * 72];    // 13.5 KB V^T (rows padded to 72)

    const int tid = threadIdx.x;
    const int wave = tid >> 6, lane = tid & 63;
    const int lrow = lane & 15, lhi = lane >> 4;
    const int bx = blockIdx.x;
    const int qt32 = 63 - (bx >> 4);
    const int kvh = (bx >> 1) & 7, bb = bx & 1;
    const int qh = kvh * 4 + wave;
    const int srow0 = bb * S_LEN + qt32 * 32;
    const int kb_last = (qt32 * 32 + 31) >> 6;
    const float cl2 = 0.10206207261596575f * 1.4426950408889634f;

    bf16x8 bq[2][3];
#pragma unroll
    for (int qt = 0; qt < 2; ++qt)
#pragma unroll
        for (int kd = 0; kd < 3; ++kd)
            bq[qt][kd] = *(const bf16x8*)(qkv + (size_t)(srow0 + qt * 16 + lrow) * QKVN +
                                          qh * 96 + kd * 32 + lhi * 8);

    float m_s[2] = {-3e38f, -3e38f}, l_s[2] = {0.0f, 0.0f};
    f32x4 oacc[6][2] = {};

    const int s0 = lrow + ((lane & 16) ? 32 : 0);
    const int s1 = s0 + 16;
    const bool khi = (lane & 32) != 0;

    const size_t kvrow0 = (size_t)(bb * S_LEN) * QKVN;
    u16x8 kreg[3], vreg[3];

    // prologue: stage tile 0 (K and V row-major, coalesced), then LDS-transpose V
    {
        const size_t kbase = kvrow0 + KOFF + (size_t)kvh * 96;
        const size_t vbase = kvrow0 + VOFF + (size_t)kvh * 96;
#pragma unroll
        for (int i = 0; i < 3; ++i) {
            const int u = tid + 256 * i;
            const int so = (u % 12) * 8, sr = u / 12;
            kreg[i] = *(const u16x8*)(qkv + kbase + (size_t)sr * QKVN + so);
            vreg[i] = *(const u16x8*)(qkv + vbase + (size_t)sr * QKVN + so);
        }
#pragma unroll
        for (int i = 0; i < 3; ++i) {
            const int u = tid + 256 * i;
            const int so = (u % 12) * 8, sr = u / 12;
            *(u16x8*)(Ks + sr * KSP + so) = kreg[i];
            *(u16x8*)(Vtmp + sr * 96 + so) = vreg[i];
        }
        __syncthreads();
#pragma unroll
        for (int i = 0; i < 3; ++i) {
            const int u = tid + 256 * i;
            const int td = u % 96, ts8 = u / 96;
            u16x8 c;
#pragma unroll
            for (int j = 0; j < 8; ++j) c[j] = Vtmp[(ts8 * 8 + j) * 96 + td];
            *(u16x8*)(Vt + td * 72 + ts8 * 8) = c;
        }
    }

    for (int kb = 0; kb <= kb_last; ++kb) {
        // T14: issue next tile's global loads before compute (latency hides under MFMA/VALU)
        if (kb < kb_last) {
            const size_t kbase2 = kvrow0 + (size_t)((kb + 1) * 64) * QKVN + KOFF + kvh * 96;
            const size_t vbase2 = kvrow0 + (size_t)((kb + 1) * 64) * QKVN + VOFF + kvh * 96;
#pragma unroll
            for (int i = 0; i < 3; ++i) {
                const int u = tid + 256 * i;
                const int so = (u % 12) * 8, sr = u / 12;
                kreg[i] = *(const u16x8*)(qkv + kbase2 + (size_t)sr * QKVN + so);
                vreg[i] = *(const u16x8*)(qkv + vbase2 + (size_t)sr * QKVN + so);
            }
        }
        __syncthreads();  // Ks/Vt of tile kb visible

        bf16x8 ka[4][3];
#pragma unroll
        for (int kt = 0; kt < 4; ++kt)
#pragma unroll
            for (int kd = 0; kd < 3; ++kd)
                ka[kt][kd] = *(const bf16x8*)(Ks + (kt * 16 + lrow) * KSP + kd * 32 + lhi * 8);

        const int qoff = qt32 * 32 - kb * 64;
        const bool lastkb = (kb == kb_last);
        u32 bp[2][2][4];

#pragma unroll
        for (int qt = 0; qt < 2; ++qt) {
            const int qrelmax = qoff + qt * 16 + 15;
            f32x4 sacc[4] = {};
#pragma unroll
            for (int kt = 0; kt < 4; ++kt) {
                if (lastkb && kt * 16 > qrelmax) continue;
#pragma unroll
                for (int kd = 0; kd < 3; ++kd)
                    sacc[kt] = __builtin_amdgcn_mfma_f32_16x16x32_bf16(ka[kt][kd], bq[qt][kd],
                                                                       sacc[kt], 0, 0, 0);
            }
            float p[4][4];
            float mx = -3e38f;
            if (lastkb) {
                const int qrel = qoff + qt * 16 + lrow;
#pragma unroll
                for (int kt = 0; kt < 4; ++kt)
#pragma unroll
                    for (int r = 0; r < 4; ++r) {
                        const bool live = (kt * 16 + lhi * 4 + r) <= qrel;
                        const float s = live ? sacc[kt][r] : -3e38f;
                        p[kt][r] = s;
                        mx = fmaxf(mx, s);
                    }
            } else {
#pragma unroll
                for (int kt = 0; kt < 4; ++kt)
#pragma unroll
                    for (int r = 0; r < 4; ++r) {
                        p[kt][r] = sacc[kt][r];
                        mx = fmaxf(mx, sacc[kt][r]);
                    }
            }
            mx = fmaxf(mx, __shfl_xor(mx, 16));
            mx = fmaxf(mx, __shfl_xor(mx, 32));
            float mn = m_s[qt];
            if (!__all(mx - mn <= 20.0f)) {
                const float mnew = fmaxf(mn, mx);
                const float alpha = exp2f((mn - mnew) * cl2);
                m_s[qt] = mnew;
                mn = mnew;
                l_s[qt] *= alpha;
#pragma unroll
                for (int dt = 0; dt < 6; ++dt)
#pragma unroll
                    for (int r = 0; r < 4; ++r) oacc[dt][qt][r] *= alpha;
            }
            float rs = 0.0f;
#pragma unroll
            for (int kt = 0; kt < 4; ++kt)
#pragma unroll
                for (int r = 0; r < 4; ++r) {
                    const float pv = exp2f((p[kt][r] - mn) * cl2);
                    p[kt][r] = pv;
                    rs += pv;
                }
            rs += __shfl_xor(rs, 16);
            rs += __shfl_xor(rs, 32);
            l_s[qt] += rs;
            u32 pk[4][2];
#pragma unroll
            for (int kt = 0; kt < 4; ++kt) {
                pk[kt][0] = cvtpk(p[kt][0], p[kt][1]);
                pk[kt][1] = cvtpk(p[kt][2], p[kt][3]);
            }
#pragma unroll
            for (int kk = 0; kk < 2; ++kk) {
                const u32 a0 = (u32)__shfl((int)pk[kk * 2][0], s0, 64);
                const u32 b0 = (u32)__shfl((int)pk[kk * 2 + 1][0], s0, 64);
                const u32 a1 = (u32)__shfl((int)pk[kk * 2][1], s0, 64);
                const u32 b1 = (u32)__shfl((int)pk[kk * 2 + 1][1], s0, 64);
                const u32 a2 = (u32)__shfl((int)pk[kk * 2][0], s1, 64);
                const u32 b2 = (u32)__shfl((int)pk[kk * 2 + 1][0], s1, 64);
                const u32 a3 = (u32)__shfl((int)pk[kk * 2][1], s1, 64);
                const u32 b3 = (u32)__shfl((int)pk[kk * 2 + 1][1], s1, 64);
                bp[qt][kk][0] = khi ? b0 : a0;
                bp[qt][kk][1] = khi ? b1 : a1;
                bp[qt][kk][2] = khi ? b2 : a2;
                bp[qt][kk][3] = khi ? b3 : a3;
            }
        }

#pragma unroll
        for (int dt = 0; dt < 6; ++dt) {
            bf16x8 va[2];
#pragma unroll
            for (int kk = 0; kk < 2; ++kk)
                va[kk] = *(const bf16x8*)(Vt + (dt * 16 + lrow) * 72 + kk * 32 + lhi * 8);
#pragma unroll
            for (int qt = 0; qt < 2; ++qt)
#pragma unroll
                for (int kk = 0; kk < 2; ++kk) {
                    const u32x4 bv = {bp[qt][kk][0], bp[qt][kk][1], bp[qt][kk][2], bp[qt][kk][3]};
                    oacc[dt][qt] = __builtin_amdgcn_mfma_f32_16x16x32_bf16(
                        va[kk], __builtin_bit_cast(bf16x8, bv), oacc[dt][qt], 0, 0, 0);
                }
        }

        __syncthreads();  // all reads of Ks/Vt/Vtmp for tile kb complete
        if (kb < kb_last) {
#pragma unroll
            for (int i = 0; i < 3; ++i) {
                const int u = tid + 256 * i;
                const int so = (u % 12) * 8, sr = u / 12;
                *(u16x8*)(Ks + sr * KSP + so) = kreg[i];
                *(u16x8*)(Vtmp + sr * 96 + so) = vreg[i];
            }
            __syncthreads();  // Vtmp visible for transpose
#pragma unroll
            for (int i = 0; i < 3; ++i) {
                const int u = tid + 256 * i;
                const int td = u % 96, ts8 = u / 96;
                u16x8 c;
#pragma unroll
                for (int j = 0; j < 8; ++j) c[j] = Vtmp[(ts8 * 8 + j) * 96 + td];
                *(u16x8*)(Vt + td * 72 + ts8 * 8) = c;
            }
        }
    }

    const size_t obase = (size_t)srow0 * EMB + qh * 96;
#pragma unroll
    for (int qt = 0; qt < 2; ++qt) {
        const float inv = 1.0f / l_s[qt];
        const size_t rbase = obase + (size_t)(qt * 16 + lrow) * EMB;
#pragma unroll
        for (int dt = 0; dt < 6; ++dt)
#pragma unroll
            for (int rp = 0; rp < 2; ++rp) {
                const u32 pair = cvtpk(oacc[dt][qt][2 * rp] * inv, oacc[dt][qt][2 * rp + 1] * inv);
                *(u32*)(out + rbase + dt * 16 + lhi * 4 + 2 * rp) = pair;
            }
    }
}

extern "C" void kernel_launch(void* const* d_in, const int* in_sizes, int n_in,
                              void* d_out, int out_size, void* d_ws, size_t ws_size,
                              hipStream_t stream) {
    const float* x = (const float*)d_in[0];
    const int* positions = (const int*)d_in[1];
    const float* W_qkv = (const float*)d_in[3];
    const float* W_o = (const float*)d_in[4];
    float* out = (float*)d_out;

    const int M = BATCH * S_LEN;               // 4096
    const size_t QKV_E = (size_t)M * QKVN;     // 18,874,368
    const size_t ATT_E = (size_t)M * EMB;      // 12,582,912
    const size_t X_E = (size_t)M * EMB;
    const size_t WQKV_E = (size_t)QKVN * EMB;  // 14,155,776 (28.3 MB bf16)
    const size_t WO_E = (size_t)EMB * EMB;     // 9,437,184

    // ws (62.9 MB): qkv [0,QKV_E) ; scratch [QKV_E,+ATT_E) = xb -> attn_out
    // d_out (50.3 MB): wqkvb (28.3 MB, dead after GEMM1)
    u16* qkv = (u16*)d_ws;
    u16* scratch = qkv + QKV_E;
    u16* xb = scratch;
    u16* wqkvb = (u16*)d_out;
    u16* wob = (u16*)d_ws;  // overwrites qkv head after attn

    conv_f2b<<<(int)(X_E / 8 / 256), 256, 0, stream>>>(x, xb, (int)(X_E / 8));
    conv_f2b<<<(int)(WQKV_E / 8 / 256), 256, 0, stream>>>(W_qkv, wqkvb, (int)(WQKV_E / 8));
    gemm_bt_p<false>
        <<<dim3(QKVN / 128, M / 128), 256, 0, stream>>>(xb, wqkvb, qkv, M, QKVN, EMB, QKVN);
    gqa_rope<<<(BATCH * S_LEN * (NQH + NKVH) * 48) / 256, 256, 0, stream>>>(qkv, positions);
    gqa_attn5<<<dim3(1024), 256, 0, stream>>>(qkv, scratch);  // overwrites xb (dead)
    conv_f2b<<<(int)(WO_E / 8 / 256), 256, 0, stream>>>(W_o, wob, (int)(WO_E / 8));
    gemm_bt_p<true>
        <<<dim3(EMB / 128, M / 128), 256, 0, stream>>>(scratch, wob, out, M, EMB, EMB, EMB);
}